// Round 5
// baseline (748.754 us; speedup 1.0000x reference)
//
#include <hip/hip_runtime.h>
#include <hip/hip_bf16.h>

// Round 18: gemm_conv v2 — tile 64Mx256N, 4 waves x (64x64 acc, 4x4 f32x4),
// double-buffered LDS (40KB), 1 barrier per K-step (stage next tile before
// computing current; __syncthreads drains vmcnt after ~200cyc of compute).
// build_t + txpose(192) fused into build_tT (writes bf16 tbT directly).
// Everything else unchanged from round 17.
// ws layout (floats):
//   yb[0,1769472) [tb hole, unused] t2b[3538944..8847360) attnb[..,8884224)
//   sc0/sh0/sc1/sh1 [8884224..8885760) zp[8885760..8885824)
//   A0 ush @f 8885824 | A1 ush @f 8941120
//   xT ush @f 9438784 | tbT ush @f 9733696
//   pk [10618432, 12387904)  -- 48x192x192 f32 partials
//   total 12,387,904 floats = 49.6 MB.

typedef __hip_bfloat16 bf16;
typedef short bf16x8 __attribute__((ext_vector_type(8)));
typedef float f32x4 __attribute__((ext_vector_type(4)));

typedef const __attribute__((address_space(1))) unsigned short* gas_ptr;
typedef __attribute__((address_space(3))) unsigned short* las_ptr;

__device__ __forceinline__ void gload16(const unsigned short* g, unsigned short* l)
{
    // direct global->LDS, 16 bytes per lane; LDS dest = wave-uniform base + lane*16
    __builtin_amdgcn_global_load_lds((gas_ptr)g, (las_ptr)l, 16, 0, 0);
}

__global__ void beacon_kernel(float* out, float val)
{
    out[threadIdx.x] = val;
}

// ------- weight reorder: src f32 [O][C][9] -> dst bf16 [O][tap*C+ci] -------
__global__ __launch_bounds__(256)
void wreorder_kernel(const float* __restrict__ src, unsigned short* __restrict__ dst,
                     int C, int n)
{
    int i = blockIdx.x * 256 + threadIdx.x;
    if (i >= n) return;
    int K = C * 9;
    int o = i / K, r = i % K;
    int tap = r / C, ci = r % C;
    float v = src[(size_t)o * K + ci * 9 + tap];
    bf16 h = __float2bfloat16(v);
    dst[i] = *reinterpret_cast<unsigned short*>(&h);
}

// ---------------- BN scale/shift precompute + zero page --------------------
__global__ __launch_bounds__(256)
void bnfold_kernel(const float* g0, const float* b0, const float* be0,
                   const float* m0, const float* v0,
                   const float* g1, const float* b1, const float* be1,
                   const float* m1, const float* v1,
                   float* sc0, float* sh0, float* sc1, float* sh1, float* zpf)
{
    int i = blockIdx.x * 256 + threadIdx.x;
    if (i < 192) {
        float s = g0[i] * rsqrtf(v0[i] + 1e-5f);
        sc0[i] = s;
        sh0[i] = (b0[i] - m0[i]) * s + be0[i];
    } else if (i < 768) {
        int c = i - 192;
        float s = g1[c] * rsqrtf(v1[c] + 1e-5f);
        sc1[c] = s;
        sh1[c] = (b1[c] - m1[c]) * s + be1[c];
    } else if (i < 832) {
        zpf[i - 768] = 0.f;
    }
}

// ------- transpose: src f32 [C][9216] -> dst bf16 [9216][C], 64x64 tiles ---
__global__ __launch_bounds__(256)
void txpose_kernel(const float* __restrict__ src, unsigned short* __restrict__ dst,
                   int C)
{
    __shared__ float tile[64][65];
    const int p0 = blockIdx.x * 64, c0 = blockIdx.y * 64;
    for (int i = threadIdx.x; i < 4096; i += 256) {
        int r = i >> 6, c = i & 63;          // r = channel-in-tile, c = pixel-in-tile
        tile[c][r] = src[(size_t)(c0 + r) * 9216 + p0 + c];
    }
    __syncthreads();
    for (int i = threadIdx.x; i < 2048; i += 256) {
        int p = i >> 5, cp = (i & 31) * 2;   // 2 channels per thread -> 4B stores
        bf16 h0 = __float2bfloat16(tile[p][cp]);
        bf16 h1 = __float2bfloat16(tile[p][cp + 1]);
        unsigned int u = (unsigned int)(*reinterpret_cast<unsigned short*>(&h0))
                       | ((unsigned int)(*reinterpret_cast<unsigned short*>(&h1)) << 16);
        *reinterpret_cast<unsigned int*>(dst + (size_t)(p0 + p) * C + c0 + cp) = u;
    }
}

// ------- fused build_t + transpose: y f32 [192][9216] -> tbT bf16 [9216][192]
// grid (144, 3): 64 pixels x 64 channels per block; channel region is
// block-uniform (c0 in {0,64,128}: max-pool+bilinear / copy / avg+bilinear).
__global__ __launch_bounds__(256)
void build_tT(const float* __restrict__ y, unsigned short* __restrict__ tbT)
{
    __shared__ float tile[64][65];
    const int p0 = blockIdx.x * 64, c0 = blockIdx.y * 64;
    for (int i = threadIdx.x; i < 4096; i += 256) {
        int r = i >> 6, pcol = i & 63;       // r = channel-in-tile, pcol = pixel
        const int c = c0 + r;
        const int pix = p0 + pcol;
        const float* yp = y + (size_t)c * 9216;
        float val;
        if (c0 == 64) {
            val = yp[pix];
        } else {
            const int oh = pix / 96, ow = pix % 96;
            float fh = fminf(fmaxf(oh * 0.5f - 0.25f, 0.f), 47.f);
            float fw = fminf(fmaxf(ow * 0.5f - 0.25f, 0.f), 47.f);
            int hlo = (int)floorf(fh);
            int wlo = (int)floorf(fw);
            int hhi = (hlo < 47) ? hlo + 1 : 47;
            int whi = (wlo < 47) ? wlo + 1 : 47;
            float ff = fh - (float)hlo;
            float fg = fw - (float)wlo;
            int hs[2] = {hlo, hhi}, wss[2] = {wlo, whi};
            float p[2][2];
            for (int a = 0; a < 2; ++a)
                for (int e = 0; e < 2; ++e) {
                    const float* q = yp + (hs[a] * 2) * 96 + wss[e] * 2;
                    float v00 = q[0], v01 = q[1], v10 = q[96], v11 = q[97];
                    p[a][e] = (c0 == 0)
                        ? fmaxf(fmaxf(v00, v01), fmaxf(v10, v11))
                        : 0.25f * (v00 + v01 + v10 + v11);
                }
            val = (p[0][0] * (1.f - ff) + p[1][0] * ff) * (1.f - fg)
                + (p[0][1] * (1.f - ff) + p[1][1] * ff) * fg;
        }
        tile[pcol][r] = val;
    }
    __syncthreads();
    for (int i = threadIdx.x; i < 2048; i += 256) {
        int p = i >> 5, cp = (i & 31) * 2;
        bf16 h0 = __float2bfloat16(tile[p][cp]);
        bf16 h1 = __float2bfloat16(tile[p][cp + 1]);
        unsigned int u = (unsigned int)(*reinterpret_cast<unsigned short*>(&h0))
                       | ((unsigned int)(*reinterpret_cast<unsigned short*>(&h1)) << 16);
        *reinterpret_cast<unsigned int*>(tbT + (size_t)(p0 + p) * 192 + c0 + cp) = u;
    }
}

// ------- implicit-im2col GEMM v2: out[M][9216] = A[M][9C] conv BT[9216][C] -
// +BN+ReLU. Tile 64(M) x 256(N), BK=32, double-buffered LDS, 1 barrier/step.
// 4 waves, each owns 64x64 (acc 4x4 f32x4). k = tap*C+ci; border lanes load
// from a zero page. gridDim = (36, M/64). Requires C % 32 == 0.
__global__ __launch_bounds__(256)
void gemm_conv(const unsigned short* __restrict__ A,
               const unsigned short* __restrict__ BT,
               const unsigned short* __restrict__ zp,
               const float* __restrict__ sc, const float* __restrict__ sh,
               float* __restrict__ out, int M, int C)
{
    __shared__ __align__(16) unsigned short As[2][64 * 32];    // 8 KB
    __shared__ __align__(16) unsigned short Bs[2][256 * 32];   // 32 KB

    const int tid  = threadIdx.x;
    const int wave = tid >> 6;
    const int lane = tid & 63;
    const int l15  = lane & 15, quad = lane >> 4;
    const int K = 9 * C;
    const int kc = C >> 5;          // K-steps per tap (2 or 6)
    const int nsteps = 9 * kc;

    const int row0 = blockIdx.y * 64;    // output-channel tile base
    const int p0   = blockIdx.x * 256;   // pixel tile base

    f32x4 acc[4][4];
#pragma unroll
    for (int m = 0; m < 4; ++m)
#pragma unroll
        for (int n = 0; n < 4; ++n) acc[m][n] = {0.f, 0.f, 0.f, 0.f};

    // staging: thread covers 16B segment row=tid>>2, shortcol=(tid&3)*8 of A,
    // and the same (row + 64r) rows of B, r=0..3.
    const int srow = tid >> 2;
    const int scol = (tid & 3) << 3;
    const unsigned short* gA = A + (size_t)(row0 + srow) * K + scol;
    int pB[4], hB[4], wB[4];
#pragma unroll
    for (int r = 0; r < 4; ++r) {
        pB[r] = p0 + 64 * r + srow;
        hB[r] = pB[r] / 96;
        wB[r] = pB[r] % 96;
    }

    // wave-uniform LDS staging bases (HW adds lane*16 bytes)
    unsigned short* lA[2] = { &As[0][wave * 512], &As[1][wave * 512] };
    unsigned short* lB[2] = { &Bs[0][wave * 512], &Bs[1][wave * 512] };

    auto STAGE = [&](int pb, int tap, int kk) {
        const int dh = tap / 3 - 1, dw = tap % 3 - 1;
        const int off = dh * 96 + dw;
        gload16(gA + tap * C + kk, lA[pb]);
#pragma unroll
        for (int r = 0; r < 4; ++r) {
            bool v = ((unsigned)(hB[r] + dh) < 96u) && ((unsigned)(wB[r] + dw) < 96u);
            const unsigned short* sB = BT + (size_t)(pB[r] + off) * C + scol + kk;
            gload16(v ? sB : zp, lB[pb] + r * 2048);
        }
    };

    STAGE(0, 0, 0);
    __syncthreads();                 // drains vmcnt: buffer 0 ready

    int tap_s = 0, kk_s = 32;        // coords of next stage
    if (kk_s == C) { kk_s = 0; tap_s = 1; }
    int pb = 0;

    for (int s = 0; s < nsteps; ++s) {
        if (s + 1 < nsteps) {
            STAGE(pb ^ 1, tap_s, kk_s);
            kk_s += 32;
            if (kk_s == C) { kk_s = 0; ++tap_s; }
        }

        bf16x8 a[4], b[4];
#pragma unroll
        for (int m = 0; m < 4; ++m)
            a[m] = *reinterpret_cast<const bf16x8*>(&As[pb][(m * 16 + l15) * 32 + quad * 8]);
#pragma unroll
        for (int n = 0; n < 4; ++n)
            b[n] = *reinterpret_cast<const bf16x8*>(&Bs[pb][(wave * 64 + n * 16 + l15) * 32 + quad * 8]);

#pragma unroll
        for (int m = 0; m < 4; ++m)
#pragma unroll
            for (int n = 0; n < 4; ++n)
                acc[m][n] = __builtin_amdgcn_mfma_f32_16x16x32_bf16(
                    a[m], b[n], acc[m][n], 0, 0, 0);

        __syncthreads();             // drains vmcnt (next tile) + frees cur buf
        pb ^= 1;
    }

#pragma unroll
    for (int m = 0; m < 4; ++m) {
        const int co = row0 + m * 16 + quad * 4;
#pragma unroll
        for (int n = 0; n < 4; ++n) {
            const int pix = p0 + wave * 64 + n * 16 + l15;
#pragma unroll
            for (int r = 0; r < 4; ++r) {
                const int c = co + r;
                float v = acc[m][n][r] * sc[c] + sh[c];
                out[(size_t)c * 9216 + pix] = fmaxf(v, 0.f);
            }
        }
    }
}

// ------------- l2norm rows (block per row, shuffle reduce) -----------------
__global__ __launch_bounds__(256)
void l2norm_rows(float* __restrict__ t2)
{
    const int c = blockIdx.x;  // 0..383
    float* p = t2 + (size_t)c * 9216;
    float s = 0.f;
    for (int i = threadIdx.x; i < 9216; i += 256) { float v = p[i]; s += v * v; }
    for (int off = 32; off; off >>= 1) s += __shfl_xor(s, off, 64);
    __shared__ float red[4];
    if ((threadIdx.x & 63) == 0) red[threadIdx.x >> 6] = s;
    __syncthreads();
    float tot = red[0] + red[1] + red[2] + red[3];
    float inv = 1.f / fmaxf(sqrtf(tot), 1e-12f);
    for (int i = threadIdx.x; i < 9216; i += 256) p[i] *= inv;
}

// -------- qk split-K partial: pk[z][c][d], 64x64 tile, 4x4 per thread ------
__global__ __launch_bounds__(256)
void qk_partial(const float* __restrict__ t2, float* __restrict__ pk)
{
    __shared__ __align__(16) float qs[32][68];
    __shared__ __align__(16) float ks[32][68];
    const int c0 = blockIdx.y * 64, d0 = blockIdx.x * 64;
    const int kbase = blockIdx.z * 192;
    const int tid = threadIdx.x, tx = tid & 15, ty = tid >> 4;
    const float* qb = t2;
    const float* kb = t2 + (size_t)192 * 9216;

    float acc[4][4];
#pragma unroll
    for (int i = 0; i < 4; ++i)
#pragma unroll
        for (int j = 0; j < 4; ++j) acc[i][j] = 0.f;

    for (int n0 = 0; n0 < 192; n0 += 32) {
        for (int i = tid; i < 512; i += 256) {
            int row = i >> 3, col = (i & 7) * 4;
            f32x4 v = *reinterpret_cast<const f32x4*>(
                qb + (size_t)(c0 + row) * 9216 + kbase + n0 + col);
            qs[col + 0][row] = v[0];
            qs[col + 1][row] = v[1];
            qs[col + 2][row] = v[2];
            qs[col + 3][row] = v[3];
            f32x4 w = *reinterpret_cast<const f32x4*>(
                kb + (size_t)(d0 + row) * 9216 + kbase + n0 + col);
            ks[col + 0][row] = w[0];
            ks[col + 1][row] = w[1];
            ks[col + 2][row] = w[2];
            ks[col + 3][row] = w[3];
        }
        __syncthreads();
#pragma unroll
        for (int kk = 0; kk < 32; ++kk) {
            f32x4 q4 = *reinterpret_cast<const f32x4*>(&qs[kk][ty * 4]);
            f32x4 k4 = *reinterpret_cast<const f32x4*>(&ks[kk][tx * 4]);
#pragma unroll
            for (int i = 0; i < 4; ++i)
#pragma unroll
                for (int j = 0; j < 4; ++j)
                    acc[i][j] += q4[i] * k4[j];
        }
        __syncthreads();
    }

    float* dst = pk + (size_t)blockIdx.z * 36864;
#pragma unroll
    for (int i = 0; i < 4; ++i)
#pragma unroll
        for (int j = 0; j < 4; ++j)
            dst[(size_t)(c0 + ty * 4 + i) * 192 + d0 + tx * 4 + j] = acc[i][j];
}

// -------- qk reduce: attn[i] = temp * sum_z pk[z][i] ------------------------
__global__ __launch_bounds__(256)
void qk_reduce(const float* __restrict__ pk, const float* __restrict__ temp,
               float* __restrict__ attn)
{
    const int i = blockIdx.x * 256 + threadIdx.x;  // 0..36863
    if (i >= 36864) return;
    float s = 0.f;
#pragma unroll
    for (int k = 0; k < 48; ++k)
        s += pk[(size_t)k * 36864 + i];
    attn[i] = s * temp[0];
}

// ---------------- softmax over last dim (192), one wave per row ------------
__global__ __launch_bounds__(64)
void softmax192(float* __restrict__ attn)
{
    float* p = attn + (size_t)blockIdx.x * 192;
    const int t = threadIdx.x;
    float e0 = p[t], e1 = p[t + 64], e2 = p[t + 128];
    float m = fmaxf(e0, fmaxf(e1, e2));
    for (int off = 32; off; off >>= 1) m = fmaxf(m, __shfl_xor(m, off, 64));
    e0 = __expf(e0 - m); e1 = __expf(e1 - m); e2 = __expf(e2 - m);
    float s = e0 + e1 + e2;
    for (int off = 32; off; off >>= 1) s += __shfl_xor(s, off, 64);
    float inv = 1.f / s;
    p[t] = e0 * inv; p[t + 64] = e1 * inv; p[t + 128] = e2 * inv;
}

// ------- ao = attn @ v; aL transposed [d][16] so inner reads are b128 ------
__global__ __launch_bounds__(256)
void attn_v(const float* __restrict__ attn, const float* __restrict__ t2,
            float* __restrict__ ao)
{
    __shared__ float aL[192 * 16];
    const int c0 = blockIdx.y * 16;
    const int n = blockIdx.x * 256 + threadIdx.x;
    for (int i = threadIdx.x; i < 3072; i += 256) {
        int d = i >> 4, cc = i & 15;
        aL[d * 16 + cc] = attn[(size_t)(c0 + cc) * 192 + d];
    }
    __syncthreads();
    const float* vb = t2 + (size_t)384 * 9216;
    f32x4 acc[4];
#pragma unroll
    for (int j = 0; j < 4; ++j) acc[j] = {0.f, 0.f, 0.f, 0.f};
    for (int d = 0; d < 192; ++d) {
        float vv = vb[(size_t)d * 9216 + n];
        const f32x4* ap = reinterpret_cast<const f32x4*>(&aL[d * 16]);
#pragma unroll
        for (int j = 0; j < 4; ++j) {
            f32x4 a = ap[j];
            acc[j][0] += a[0] * vv;
            acc[j][1] += a[1] * vv;
            acc[j][2] += a[2] * vv;
            acc[j][3] += a[3] * vv;
        }
    }
#pragma unroll
    for (int j = 0; j < 4; ++j)
#pragma unroll
        for (int r = 0; r < 4; ++r)
            ao[(size_t)(c0 + j * 4 + r) * 9216 + n] = acc[j][r];
}

// ---------------- depthwise 3x3 + bias -> fp32 out -------------------------
__global__ __launch_bounds__(256)
void dwconv(const float* __restrict__ ao, const float* __restrict__ w2,
            const float* __restrict__ bias2, float* __restrict__ out)
{
    const int c = blockIdx.y;
    const int pix = blockIdx.x * 256 + threadIdx.x;
    const int h = pix / 96, w = pix % 96;
    const float* sp = ao + (size_t)c * 9216;
    float acc = bias2[c];
#pragma unroll
    for (int kh = 0; kh < 3; ++kh) {
        int hh = h + kh - 1;
        if (hh < 0 || hh >= 96) continue;
#pragma unroll
        for (int kw = 0; kw < 3; ++kw) {
            int ww = w + kw - 1;
            if (ww < 0 || ww >= 96) continue;
            acc += w2[c * 9 + kh * 3 + kw] * sp[hh * 96 + ww];
        }
    }
    out[(size_t)c * 9216 + pix] = acc;
}

extern "C" void kernel_launch(void* const* d_in, const int* in_sizes, int n_in,
                              void* d_out, int out_size, void* d_ws, size_t ws_size,
                              hipStream_t stream)
{
    float* out = (float*)d_out;

    static const int expected_sizes[16] = {
        2359296, 110592, 192, 192, 192, 192, 192,
        995328, 576, 576, 576, 576, 576, 1, 1728, 192
    };
    if (n_in != 16) {
        beacon_kernel<<<1, 256, 0, stream>>>(out, 100000.f + (float)n_in);
        return;
    }
    for (int i = 0; i < 16; ++i) {
        if (in_sizes[i] != expected_sizes[i]) {
            beacon_kernel<<<1, 256, 0, stream>>>(out, 1000.f * (float)(i + 1));
            return;
        }
    }
    if (out_size != 7077888) {
        beacon_kernel<<<1, 256, 0, stream>>>(out, 50000.f);
        return;
    }
    const size_t needed = (size_t)12387904 * 4;  // 49.6 MB
    if (ws_size < needed) {
        beacon_kernel<<<1, 256, 0, stream>>>(out, 200.f + (float)(ws_size >> 20));
        return;
    }

    const float* x    = (const float*)d_in[0];
    const float* w0   = (const float*)d_in[1];
    const float* b0   = (const float*)d_in[2];
    const float* g0   = (const float*)d_in[3];
    const float* be0  = (const float*)d_in[4];
    const float* m0   = (const float*)d_in[5];
    const float* v0   = (const float*)d_in[6];
    const float* w1   = (const float*)d_in[7];
    const float* b1   = (const float*)d_in[8];
    const float* g1   = (const float*)d_in[9];
    const float* be1  = (const float*)d_in[10];
    const float* m1   = (const float*)d_in[11];
    const float* v1   = (const float*)d_in[12];
    const float* temp = (const float*)d_in[13];
    const float* w2   = (const float*)d_in[14];
    const float* bi2  = (const float*)d_in[15];

    float* ws    = (float*)d_ws;
    float* yb    = ws;                       // 1,769,472 f
    float* t2b   = ws + 3538944;             // 5,308,416 f
    float* attnb = ws + 8847360;             // 36,864 f
    float* sc0   = ws + 8884224;
    float* sh0   = ws + 8884416;
    float* sc1   = ws + 8884608;
    float* sh1   = ws + 8885184;
    float* zpf   = ws + 8885760;             // 64 f zero page
    unsigned short* zp  = (unsigned short*)zpf;
    unsigned short* A0  = (unsigned short*)(ws + 8885824);   // 110,592 bf16
    unsigned short* A1  = (unsigned short*)(ws + 8941120);   // 995,328 bf16
    unsigned short* xT  = (unsigned short*)(ws + 9438784);   // 9216x64 bf16
    unsigned short* tbT = (unsigned short*)(ws + 9733696);   // 9216x192 bf16
    float* pk  = ws + 10618432;              // 48x192x192 f
    float* aob = yb;  // alias: yb dead after build_tT

    wreorder_kernel<<<dim3(432), dim3(256), 0, stream>>>(w0, A0, 64, 110592);
    wreorder_kernel<<<dim3(3888), dim3(256), 0, stream>>>(w1, A1, 192, 995328);
    bnfold_kernel<<<dim3(4), dim3(256), 0, stream>>>(g0, b0, be0, m0, v0,
                                                     g1, b1, be1, m1, v1,
                                                     sc0, sh0, sc1, sh1, zpf);

    for (int b = 0; b < 4; ++b) {
        const float* xb = x + (size_t)b * 64 * 9216;
        float* outb = out + (size_t)b * 192 * 9216;
        txpose_kernel<<<dim3(144, 1), dim3(256), 0, stream>>>(xb, xT, 64);
        gemm_conv<<<dim3(36, 3), dim3(256), 0, stream>>>(A0, xT, zp, sc0, sh0, yb, 192, 64);
        build_tT<<<dim3(144, 3), dim3(256), 0, stream>>>(yb, tbT);
        gemm_conv<<<dim3(36, 9), dim3(256), 0, stream>>>(A1, tbT, zp, sc1, sh1, t2b, 576, 192);
        l2norm_rows<<<dim3(384), dim3(256), 0, stream>>>(t2b);
        qk_partial<<<dim3(3, 3, 48), dim3(256), 0, stream>>>(t2b, pk);
        qk_reduce<<<dim3(144), dim3(256), 0, stream>>>(pk, temp, attnb);
        softmax192<<<dim3(192), dim3(64), 0, stream>>>(attnb);
        attn_v<<<dim3(36, 12), dim3(256), 0, stream>>>(attnb, t2b, aob);
        dwconv<<<dim3(36, 192), dim3(256), 0, stream>>>(aob, w2, bi2, outb);
    }
}

// Round 6
// 483.868 us; speedup vs baseline: 1.5474x; 1.5474x over previous
//
#include <hip/hip_runtime.h>
#include <hip/hip_bf16.h>

// Round 19: stage-major batching + gemm back to 64x128 w/ double-buffer.
// All kernels take blockIdx.z (or .y) = batch; 13 launches total (was 51).
// gemm_conv: 64Mx128N, BK=32, dbuf LDS 24KB, 1 barrier/step, grid
// (72, M/64, 4) -> conv2 = 2592 blocks (~10/CU; round-18's 64x256 had 324
// blocks = 11% occupancy -> regression). qk split-K = 8 chunks x 1152.
// ws layout (floats), total 34,911,808 f = 139.6 MB (<141.6MB evidenced):
//   yb[0,7077888) t2b[..,28311552) attnb[..,28459008)
//   sc0@28459008 sh0@28459200 sc1@28459392 sh1@28459968 zp@28460544
//   A0 ush @f 28460608 | A1 ush @f 28515904
//   xT ush @f 29013568 | tbT ush @f 30193216
//   pk [33732160, 34911808)  -- [b][8][192][192] f32 partials

typedef __hip_bfloat16 bf16;
typedef short bf16x8 __attribute__((ext_vector_type(8)));
typedef float f32x4 __attribute__((ext_vector_type(4)));

typedef const __attribute__((address_space(1))) unsigned short* gas_ptr;
typedef __attribute__((address_space(3))) unsigned short* las_ptr;

__device__ __forceinline__ void gload16(const unsigned short* g, unsigned short* l)
{
    __builtin_amdgcn_global_load_lds((gas_ptr)g, (las_ptr)l, 16, 0, 0);
}

__global__ void beacon_kernel(float* out, float val)
{
    out[threadIdx.x] = val;
}

// ------- weight reorder: src f32 [O][C][9] -> dst bf16 [O][tap*C+ci] -------
__global__ __launch_bounds__(256)
void wreorder_kernel(const float* __restrict__ src, unsigned short* __restrict__ dst,
                     int C, int n)
{
    int i = blockIdx.x * 256 + threadIdx.x;
    if (i >= n) return;
    int K = C * 9;
    int o = i / K, r = i % K;
    int tap = r / C, ci = r % C;
    float v = src[(size_t)o * K + ci * 9 + tap];
    bf16 h = __float2bfloat16(v);
    dst[i] = *reinterpret_cast<unsigned short*>(&h);
}

// ---------------- BN scale/shift precompute + zero page --------------------
__global__ __launch_bounds__(256)
void bnfold_kernel(const float* g0, const float* b0, const float* be0,
                   const float* m0, const float* v0,
                   const float* g1, const float* b1, const float* be1,
                   const float* m1, const float* v1,
                   float* sc0, float* sh0, float* sc1, float* sh1, float* zpf)
{
    int i = blockIdx.x * 256 + threadIdx.x;
    if (i < 192) {
        float s = g0[i] * rsqrtf(v0[i] + 1e-5f);
        sc0[i] = s;
        sh0[i] = (b0[i] - m0[i]) * s + be0[i];
    } else if (i < 768) {
        int c = i - 192;
        float s = g1[c] * rsqrtf(v1[c] + 1e-5f);
        sc1[c] = s;
        sh1[c] = (b1[c] - m1[c]) * s + be1[c];
    } else if (i < 832) {
        zpf[i - 768] = 0.f;
    }
}

// ------- transpose: x f32 [B][64][9216] -> xT bf16 [B][9216][64] -----------
// grid (144, 1, B)
__global__ __launch_bounds__(256)
void txpose_kernel(const float* __restrict__ src, unsigned short* __restrict__ dst,
                   int C)
{
    __shared__ float tile[64][65];
    const int p0 = blockIdx.x * 64, c0 = blockIdx.y * 64;
    src += (size_t)blockIdx.z * C * 9216;
    dst += (size_t)blockIdx.z * 9216 * C;
    for (int i = threadIdx.x; i < 4096; i += 256) {
        int r = i >> 6, c = i & 63;
        tile[c][r] = src[(size_t)(c0 + r) * 9216 + p0 + c];
    }
    __syncthreads();
    for (int i = threadIdx.x; i < 2048; i += 256) {
        int p = i >> 5, cp = (i & 31) * 2;
        bf16 h0 = __float2bfloat16(tile[p][cp]);
        bf16 h1 = __float2bfloat16(tile[p][cp + 1]);
        unsigned int u = (unsigned int)(*reinterpret_cast<unsigned short*>(&h0))
                       | ((unsigned int)(*reinterpret_cast<unsigned short*>(&h1)) << 16);
        *reinterpret_cast<unsigned int*>(dst + (size_t)(p0 + p) * C + c0 + cp) = u;
    }
}

// ------- fused build_t + transpose: y f32 [B][192][9216] -> tbT bf16 [B][9216][192]
// grid (144, 3, B)
__global__ __launch_bounds__(256)
void build_tT(const float* __restrict__ y, unsigned short* __restrict__ tbT)
{
    __shared__ float tile[64][65];
    const int p0 = blockIdx.x * 64, c0 = blockIdx.y * 64;
    y += (size_t)blockIdx.z * 192 * 9216;
    tbT += (size_t)blockIdx.z * 9216 * 192;
    for (int i = threadIdx.x; i < 4096; i += 256) {
        int r = i >> 6, pcol = i & 63;
        const int c = c0 + r;
        const int pix = p0 + pcol;
        const float* yp = y + (size_t)c * 9216;
        float val;
        if (c0 == 64) {
            val = yp[pix];
        } else {
            const int oh = pix / 96, ow = pix % 96;
            float fh = fminf(fmaxf(oh * 0.5f - 0.25f, 0.f), 47.f);
            float fw = fminf(fmaxf(ow * 0.5f - 0.25f, 0.f), 47.f);
            int hlo = (int)floorf(fh);
            int wlo = (int)floorf(fw);
            int hhi = (hlo < 47) ? hlo + 1 : 47;
            int whi = (wlo < 47) ? wlo + 1 : 47;
            float ff = fh - (float)hlo;
            float fg = fw - (float)wlo;
            int hs[2] = {hlo, hhi}, wss[2] = {wlo, whi};
            float p[2][2];
            for (int a = 0; a < 2; ++a)
                for (int e = 0; e < 2; ++e) {
                    const float* q = yp + (hs[a] * 2) * 96 + wss[e] * 2;
                    float v00 = q[0], v01 = q[1], v10 = q[96], v11 = q[97];
                    p[a][e] = (c0 == 0)
                        ? fmaxf(fmaxf(v00, v01), fmaxf(v10, v11))
                        : 0.25f * (v00 + v01 + v10 + v11);
                }
            val = (p[0][0] * (1.f - ff) + p[1][0] * ff) * (1.f - fg)
                + (p[0][1] * (1.f - ff) + p[1][1] * ff) * fg;
        }
        tile[pcol][r] = val;
    }
    __syncthreads();
    for (int i = threadIdx.x; i < 2048; i += 256) {
        int p = i >> 5, cp = (i & 31) * 2;
        bf16 h0 = __float2bfloat16(tile[p][cp]);
        bf16 h1 = __float2bfloat16(tile[p][cp + 1]);
        unsigned int u = (unsigned int)(*reinterpret_cast<unsigned short*>(&h0))
                       | ((unsigned int)(*reinterpret_cast<unsigned short*>(&h1)) << 16);
        *reinterpret_cast<unsigned int*>(tbT + (size_t)(p0 + p) * 192 + c0 + cp) = u;
    }
}

// ------- implicit-im2col GEMM: out[B][M][9216] = A[M][9C] conv BT[B][9216][C]
// +BN+ReLU. Tile 64(M) x 128(N), BK=32, double-buffered LDS (24KB), 1 barrier
// per K-step. 4 waves x (64x32 acc). gridDim = (72, M/64, B). C % 32 == 0.
__global__ __launch_bounds__(256)
void gemm_conv(const unsigned short* __restrict__ A,
               const unsigned short* __restrict__ BT,
               const unsigned short* __restrict__ zp,
               const float* __restrict__ sc, const float* __restrict__ sh,
               float* __restrict__ out, int M, int C)
{
    __shared__ __align__(16) unsigned short As[2][64 * 32];    // 8 KB
    __shared__ __align__(16) unsigned short Bs[2][128 * 32];   // 16 KB

    const int tid  = threadIdx.x;
    const int wave = tid >> 6;
    const int lane = tid & 63;
    const int l15  = lane & 15, quad = lane >> 4;
    const int K = 9 * C;
    const int kc = C >> 5;           // K-steps per tap
    const int nsteps = 9 * kc;

    BT  += (size_t)blockIdx.z * 9216 * C;
    out += (size_t)blockIdx.z * (size_t)M * 9216;

    const int row0 = blockIdx.y * 64;
    const int p0   = blockIdx.x * 128;

    f32x4 acc[4][2];
#pragma unroll
    for (int m = 0; m < 4; ++m)
#pragma unroll
        for (int n = 0; n < 2; ++n) acc[m][n] = {0.f, 0.f, 0.f, 0.f};

    const int srow = tid >> 2;
    const int scol = (tid & 3) << 3;
    const unsigned short* gA = A + (size_t)(row0 + srow) * K + scol;
    const int pB0 = p0 + srow,      hB0 = pB0 / 96, wB0 = pB0 % 96;
    const int pB1 = p0 + 64 + srow, hB1 = pB1 / 96, wB1 = pB1 % 96;

    unsigned short* lA[2] = { &As[0][wave * 512], &As[1][wave * 512] };
    unsigned short* lB0[2] = { &Bs[0][wave * 512], &Bs[1][wave * 512] };
    unsigned short* lB1[2] = { &Bs[0][2048 + wave * 512], &Bs[1][2048 + wave * 512] };

    auto STAGE = [&](int pb, int tap, int kk) {
        const int dh = tap / 3 - 1, dw = tap % 3 - 1;
        const int off = dh * 96 + dw;
        gload16(gA + tap * C + kk, lA[pb]);
        bool v0 = ((unsigned)(hB0 + dh) < 96u) && ((unsigned)(wB0 + dw) < 96u);
        bool v1 = ((unsigned)(hB1 + dh) < 96u) && ((unsigned)(wB1 + dw) < 96u);
        const unsigned short* s0 = BT + (size_t)(pB0 + off) * C + scol + kk;
        const unsigned short* s1 = BT + (size_t)(pB1 + off) * C + scol + kk;
        gload16(v0 ? s0 : zp, lB0[pb]);
        gload16(v1 ? s1 : zp, lB1[pb]);
    };

    STAGE(0, 0, 0);
    __syncthreads();

    int tap_s = 0, kk_s = 32;
    if (kk_s == C) { kk_s = 0; tap_s = 1; }
    int pb = 0;

    for (int s = 0; s < nsteps; ++s) {
        if (s + 1 < nsteps) {
            STAGE(pb ^ 1, tap_s, kk_s);
            kk_s += 32;
            if (kk_s == C) { kk_s = 0; ++tap_s; }
        }

        bf16x8 a[4], b[2];
#pragma unroll
        for (int m = 0; m < 4; ++m)
            a[m] = *reinterpret_cast<const bf16x8*>(&As[pb][(m * 16 + l15) * 32 + quad * 8]);
#pragma unroll
        for (int n = 0; n < 2; ++n)
            b[n] = *reinterpret_cast<const bf16x8*>(&Bs[pb][(wave * 32 + n * 16 + l15) * 32 + quad * 8]);

#pragma unroll
        for (int m = 0; m < 4; ++m)
#pragma unroll
            for (int n = 0; n < 2; ++n)
                acc[m][n] = __builtin_amdgcn_mfma_f32_16x16x32_bf16(
                    a[m], b[n], acc[m][n], 0, 0, 0);

        __syncthreads();
        pb ^= 1;
    }

#pragma unroll
    for (int m = 0; m < 4; ++m) {
        const int co = row0 + m * 16 + quad * 4;
#pragma unroll
        for (int n = 0; n < 2; ++n) {
            const int pix = p0 + wave * 32 + n * 16 + l15;
#pragma unroll
            for (int r = 0; r < 4; ++r) {
                const int c = co + r;
                float v = acc[m][n][r] * sc[c] + sh[c];
                out[(size_t)c * 9216 + pix] = fmaxf(v, 0.f);
            }
        }
    }
}

// ------------- l2norm rows (block per row, shuffle reduce) -----------------
// grid (384, B): rows 0..383 of each batch's t2 (q and k sections)
__global__ __launch_bounds__(256)
void l2norm_rows(float* __restrict__ t2)
{
    const int c = blockIdx.x;
    float* p = t2 + (size_t)blockIdx.y * 5308416 + (size_t)c * 9216;
    float s = 0.f;
    for (int i = threadIdx.x; i < 9216; i += 256) { float v = p[i]; s += v * v; }
    for (int off = 32; off; off >>= 1) s += __shfl_xor(s, off, 64);
    __shared__ float red[4];
    if ((threadIdx.x & 63) == 0) red[threadIdx.x >> 6] = s;
    __syncthreads();
    float tot = red[0] + red[1] + red[2] + red[3];
    float inv = 1.f / fmaxf(sqrtf(tot), 1e-12f);
    for (int i = threadIdx.x; i < 9216; i += 256) p[i] *= inv;
}

// -------- qk split-K partial: pk[b][z][c][d], 64x64 tile, 4x4/thread -------
// grid (3,3,8*B): z = b*8+chunk, K-chunk 1152, BK=32.
__global__ __launch_bounds__(256)
void qk_partial(const float* __restrict__ t2, float* __restrict__ pk)
{
    __shared__ __align__(16) float qs[32][68];
    __shared__ __align__(16) float ks[32][68];
    const int c0 = blockIdx.y * 64, d0 = blockIdx.x * 64;
    const int bz = blockIdx.z, bb = bz >> 3, chunk = bz & 7;
    const int kbase = chunk * 1152;
    const int tid = threadIdx.x, tx = tid & 15, ty = tid >> 4;
    const float* qb = t2 + (size_t)bb * 5308416;
    const float* kb = qb + (size_t)192 * 9216;

    float acc[4][4];
#pragma unroll
    for (int i = 0; i < 4; ++i)
#pragma unroll
        for (int j = 0; j < 4; ++j) acc[i][j] = 0.f;

    for (int n0 = 0; n0 < 1152; n0 += 32) {
        for (int i = tid; i < 512; i += 256) {
            int row = i >> 3, col = (i & 7) * 4;
            f32x4 v = *reinterpret_cast<const f32x4*>(
                qb + (size_t)(c0 + row) * 9216 + kbase + n0 + col);
            qs[col + 0][row] = v[0];
            qs[col + 1][row] = v[1];
            qs[col + 2][row] = v[2];
            qs[col + 3][row] = v[3];
            f32x4 w = *reinterpret_cast<const f32x4*>(
                kb + (size_t)(d0 + row) * 9216 + kbase + n0 + col);
            ks[col + 0][row] = w[0];
            ks[col + 1][row] = w[1];
            ks[col + 2][row] = w[2];
            ks[col + 3][row] = w[3];
        }
        __syncthreads();
#pragma unroll
        for (int kk = 0; kk < 32; ++kk) {
            f32x4 q4 = *reinterpret_cast<const f32x4*>(&qs[kk][ty * 4]);
            f32x4 k4 = *reinterpret_cast<const f32x4*>(&ks[kk][tx * 4]);
#pragma unroll
            for (int i = 0; i < 4; ++i)
#pragma unroll
                for (int j = 0; j < 4; ++j)
                    acc[i][j] += q4[i] * k4[j];
        }
        __syncthreads();
    }

    float* dst = pk + (size_t)bz * 36864;
#pragma unroll
    for (int i = 0; i < 4; ++i)
#pragma unroll
        for (int j = 0; j < 4; ++j)
            dst[(size_t)(c0 + ty * 4 + i) * 192 + d0 + tx * 4 + j] = acc[i][j];
}

// -------- qk reduce: attn[b][i] = temp * sum_z pk[b][z][i]; grid (144,B) ---
__global__ __launch_bounds__(256)
void qk_reduce(const float* __restrict__ pk, const float* __restrict__ temp,
               float* __restrict__ attn)
{
    const int i = blockIdx.x * 256 + threadIdx.x;
    if (i >= 36864) return;
    const int bb = blockIdx.y;
    const float* src = pk + (size_t)bb * 8 * 36864;
    float s = 0.f;
#pragma unroll
    for (int k = 0; k < 8; ++k)
        s += src[(size_t)k * 36864 + i];
    attn[(size_t)bb * 36864 + i] = s * temp[0];
}

// ---------------- softmax over last dim (192); grid (192*B) ----------------
__global__ __launch_bounds__(64)
void softmax192(float* __restrict__ attn)
{
    float* p = attn + (size_t)blockIdx.x * 192;
    const int t = threadIdx.x;
    float e0 = p[t], e1 = p[t + 64], e2 = p[t + 128];
    float m = fmaxf(e0, fmaxf(e1, e2));
    for (int off = 32; off; off >>= 1) m = fmaxf(m, __shfl_xor(m, off, 64));
    e0 = __expf(e0 - m); e1 = __expf(e1 - m); e2 = __expf(e2 - m);
    float s = e0 + e1 + e2;
    for (int off = 32; off; off >>= 1) s += __shfl_xor(s, off, 64);
    float inv = 1.f / s;
    p[t] = e0 * inv; p[t + 64] = e1 * inv; p[t + 128] = e2 * inv;
}

// ------- ao = attn @ v; grid (36, 12, B) -----------------------------------
__global__ __launch_bounds__(256)
void attn_v(const float* __restrict__ attn, const float* __restrict__ t2,
            float* __restrict__ ao)
{
    __shared__ float aL[192 * 16];
    const int c0 = blockIdx.y * 16;
    const int n = blockIdx.x * 256 + threadIdx.x;
    attn += (size_t)blockIdx.z * 36864;
    t2   += (size_t)blockIdx.z * 5308416;
    ao   += (size_t)blockIdx.z * 1769472;
    for (int i = threadIdx.x; i < 3072; i += 256) {
        int d = i >> 4, cc = i & 15;
        aL[d * 16 + cc] = attn[(size_t)(c0 + cc) * 192 + d];
    }
    __syncthreads();
    const float* vb = t2 + (size_t)384 * 9216;
    f32x4 acc[4];
#pragma unroll
    for (int j = 0; j < 4; ++j) acc[j] = {0.f, 0.f, 0.f, 0.f};
    for (int d = 0; d < 192; ++d) {
        float vv = vb[(size_t)d * 9216 + n];
        const f32x4* ap = reinterpret_cast<const f32x4*>(&aL[d * 16]);
#pragma unroll
        for (int j = 0; j < 4; ++j) {
            f32x4 a = ap[j];
            acc[j][0] += a[0] * vv;
            acc[j][1] += a[1] * vv;
            acc[j][2] += a[2] * vv;
            acc[j][3] += a[3] * vv;
        }
    }
#pragma unroll
    for (int j = 0; j < 4; ++j)
#pragma unroll
        for (int r = 0; r < 4; ++r)
            ao[(size_t)(c0 + j * 4 + r) * 9216 + n] = acc[j][r];
}

// ---------------- depthwise 3x3 + bias -> fp32 out; grid (36,192,B) --------
__global__ __launch_bounds__(256)
void dwconv(const float* __restrict__ ao, const float* __restrict__ w2,
            const float* __restrict__ bias2, float* __restrict__ out)
{
    const int c = blockIdx.y;
    const int pix = blockIdx.x * 256 + threadIdx.x;
    const int h = pix / 96, w = pix % 96;
    const float* sp = ao + (size_t)blockIdx.z * 1769472 + (size_t)c * 9216;
    float acc = bias2[c];
#pragma unroll
    for (int kh = 0; kh < 3; ++kh) {
        int hh = h + kh - 1;
        if (hh < 0 || hh >= 96) continue;
#pragma unroll
        for (int kw = 0; kw < 3; ++kw) {
            int ww = w + kw - 1;
            if (ww < 0 || ww >= 96) continue;
            acc += w2[c * 9 + kh * 3 + kw] * sp[hh * 96 + ww];
        }
    }
    out[(size_t)blockIdx.z * 1769472 + (size_t)c * 9216 + pix] = acc;
}

extern "C" void kernel_launch(void* const* d_in, const int* in_sizes, int n_in,
                              void* d_out, int out_size, void* d_ws, size_t ws_size,
                              hipStream_t stream)
{
    float* out = (float*)d_out;

    static const int expected_sizes[16] = {
        2359296, 110592, 192, 192, 192, 192, 192,
        995328, 576, 576, 576, 576, 576, 1, 1728, 192
    };
    if (n_in != 16) {
        beacon_kernel<<<1, 256, 0, stream>>>(out, 100000.f + (float)n_in);
        return;
    }
    for (int i = 0; i < 16; ++i) {
        if (in_sizes[i] != expected_sizes[i]) {
            beacon_kernel<<<1, 256, 0, stream>>>(out, 1000.f * (float)(i + 1));
            return;
        }
    }
    if (out_size != 7077888) {
        beacon_kernel<<<1, 256, 0, stream>>>(out, 50000.f);
        return;
    }
    const size_t needed = (size_t)34911808 * 4;  // 139.6 MB
    if (ws_size < needed) {
        beacon_kernel<<<1, 256, 0, stream>>>(out, 200.f + (float)(ws_size >> 20));
        return;
    }

    const float* x    = (const float*)d_in[0];
    const float* w0   = (const float*)d_in[1];
    const float* b0   = (const float*)d_in[2];
    const float* g0   = (const float*)d_in[3];
    const float* be0  = (const float*)d_in[4];
    const float* m0   = (const float*)d_in[5];
    const float* v0   = (const float*)d_in[6];
    const float* w1   = (const float*)d_in[7];
    const float* b1   = (const float*)d_in[8];
    const float* g1   = (const float*)d_in[9];
    const float* be1  = (const float*)d_in[10];
    const float* m1   = (const float*)d_in[11];
    const float* v1   = (const float*)d_in[12];
    const float* temp = (const float*)d_in[13];
    const float* w2   = (const float*)d_in[14];
    const float* bi2  = (const float*)d_in[15];

    float* ws    = (float*)d_ws;
    float* yb    = ws;                        // 4 x 1,769,472 f
    float* t2b   = ws + 7077888;              // 4 x 5,308,416 f
    float* attnb = ws + 28311552;             // 4 x 36,864 f
    float* sc0   = ws + 28459008;
    float* sh0   = ws + 28459200;
    float* sc1   = ws + 28459392;
    float* sh1   = ws + 28459968;
    float* zpf   = ws + 28460544;             // 64 f zero page
    unsigned short* zp  = (unsigned short*)zpf;
    unsigned short* A0  = (unsigned short*)(ws + 28460608);  // 110,592 bf16
    unsigned short* A1  = (unsigned short*)(ws + 28515904);  // 995,328 bf16
    unsigned short* xT  = (unsigned short*)(ws + 29013568);  // 4 x 9216x64 bf16
    unsigned short* tbT = (unsigned short*)(ws + 30193216);  // 4 x 9216x192 bf16
    float* pk  = ws + 33732160;               // 4 x 8 x 36864 f
    float* aob = yb;  // alias: yb dead after build_tT

    wreorder_kernel<<<dim3(432), dim3(256), 0, stream>>>(w0, A0, 64, 110592);
    wreorder_kernel<<<dim3(3888), dim3(256), 0, stream>>>(w1, A1, 192, 995328);
    bnfold_kernel<<<dim3(4), dim3(256), 0, stream>>>(g0, b0, be0, m0, v0,
                                                     g1, b1, be1, m1, v1,
                                                     sc0, sh0, sc1, sh1, zpf);

    txpose_kernel<<<dim3(144, 1, 4), dim3(256), 0, stream>>>(x, xT, 64);
    gemm_conv<<<dim3(72, 3, 4), dim3(256), 0, stream>>>(A0, xT, zp, sc0, sh0, yb, 192, 64);
    build_tT<<<dim3(144, 3, 4), dim3(256), 0, stream>>>(yb, tbT);
    gemm_conv<<<dim3(72, 9, 4), dim3(256), 0, stream>>>(A1, tbT, zp, sc1, sh1, t2b, 576, 192);
    l2norm_rows<<<dim3(384, 4), dim3(256), 0, stream>>>(t2b);
    qk_partial<<<dim3(3, 3, 32), dim3(256), 0, stream>>>(t2b, pk);
    qk_reduce<<<dim3(144, 4), dim3(256), 0, stream>>>(pk, temp, attnb);
    softmax192<<<dim3(768), dim3(64), 0, stream>>>(attnb);
    attn_v<<<dim3(36, 12, 4), dim3(256), 0, stream>>>(attnb, t2b, aob);
    dwconv<<<dim3(36, 192, 4), dim3(256), 0, stream>>>(aob, w2, bi2, out);
}